// Round 9
// baseline (338.705 us; speedup 1.0000x reference)
//
#include <hip/hip_runtime.h>
#include <float.h>

// Problem constants
#define NROWS 65536      // B*H*W*D
#define CDIM  256
#define KS    1024
#define KY    512
#define KTOT  1536
#define SPB   4096       // H*W*D per batch

// ---- workspace byte offsets ----
#define WB_CNT_S       0         // 1024 int
#define WB_CNT_Y       4096      // 512 int
#define WB_RESCUE_CNT  6144      // 2 int
#define WB_DISACC      6152      // 1 float
#define WB_DW_S        6400      // 1024*256 f32
#define WB_DW_Y        1054976   // 512*256 f32
#define WB_ZERO_BYTES  1579264   // memset [0, here): cnt, rescue_cnt, disacc, dw
#define WB_EIMG        1579264   // 96 chunks * 8192 B (fp16 image, 16 codes/chunk)
#define WB_EN2         2365696   // 1536 f32
#define WB_IDXS_I      2371840   // 65536 int
#define WB_IDXY_I      2633984   // 65536 int
#define WB_RLIST_S     2896128   // 65536 int
#define WB_RLIST_Y     3158272   // 65536 int
#define WB_BASE_S      3420416   // 1024 int
#define WB_BASE_Y      3424512   // 512 int
#define WB_CUR_S       3426560   // 1024 int
#define WB_CUR_Y       3430656   // 512 int
#define WB_SCALE_S     3432704   // 1024 f32
#define WB_SCALE_Y     3436800   // 512 f32
#define WB_PERM_S      3438848   // 65536 int
#define WB_PERM_Y      3700992   // 65536 int
#define WB_KSORT_S     3963136   // 65536 int
#define WB_KSORT_Y     4225280   // 65536 int
#define WB_EMB_S       4487424   // 1024*256 f32
#define WB_EMB_Y       5536000   // 512*256 f32

// ---- output float offsets ----
#define OFF_OUT_ZQ   0
#define OFF_OUT_DIS  16777216
#define OFF_OUT_SIDX 16777217
#define OFF_OUT_YIDX 16842753

typedef __attribute__((ext_vector_type(8)))  _Float16 f16x8;
typedef __attribute__((ext_vector_type(4)))  float    f32x4;

__device__ __forceinline__ unsigned int umn(unsigned int a, unsigned int b) { return a < b ? a : b; }
__device__ __forceinline__ unsigned int umx(unsigned int a, unsigned int b) { return a > b ? a : b; }

// ---------------------------------------------------------------------------
// Codebook prep -> fp16 fragment image for 16x16x32 MFMA B-operand.
// Chunk = 16 codes = 8KB. Within chunk: kc(0..7) blocks of 1KB; within block
// lane l reads 16B at l*16 = code (l&15), channels kc*32 + (l>>4)*8 + j.
__global__ void prep_e(const float* __restrict__ Es, const float* __restrict__ Ey,
                       unsigned short* __restrict__ eimg, float* __restrict__ en2) {
    int k = blockIdx.x;            // 0..1535 global code
    int lane = threadIdx.x;        // 64
    const float* E = (k < KS) ? (Es + (size_t)k * CDIM) : (Ey + (size_t)(k - KS) * CDIM);
    float4 v = *(const float4*)(E + lane * 4);
    float nrm = v.x * v.x + v.y * v.y + v.z * v.z + v.w * v.w;
#pragma unroll
    for (int off = 32; off > 0; off >>= 1) nrm += __shfl_down(nrm, off);
    if (lane == 0) en2[k] = nrm;

    unsigned short q0 = __builtin_bit_cast(unsigned short, (_Float16)v.x);
    unsigned short q1 = __builtin_bit_cast(unsigned short, (_Float16)v.y);
    unsigned short q2 = __builtin_bit_cast(unsigned short, (_Float16)v.z);
    unsigned short q3 = __builtin_bit_cast(unsigned short, (_Float16)v.w);
    uint2 hp = make_uint2((unsigned)q0 | ((unsigned)q1 << 16),
                          (unsigned)q2 | ((unsigned)q3 << 16));

    int c0 = lane * 4;
    int kc = c0 >> 5, g = (c0 >> 3) & 3, j0 = c0 & 7;   // j0 in {0,4}
    size_t byteoff = (size_t)(k >> 4) * 8192 + (size_t)kc * 1024
                   + (size_t)(g * 16 + (k & 15)) * 16 + (size_t)j0 * 2;
    *(uint2*)((char*)eimg + byteoff) = hp;
}

// ---------------------------------------------------------------------------
// Transpose z -> zf[n][c] fp32 (written into d_out zq region as scratch).
__global__ void prep_z(const float* __restrict__ z, float* __restrict__ zf) {
    __shared__ float Zs[32][257];
    int blk = blockIdx.x;          // 2048
    int n0 = blk * 32, b = n0 >> 12, s0 = n0 & 4095;
    int t = threadIdx.x;
    const float* zb = z + (size_t)b * CDIM * SPB + s0;
#pragma unroll
    for (int i = 0; i < 32; ++i) {
        int l = i * 256 + t;       // c*32 + s
        int c = l >> 5, s = l & 31;
        Zs[s][c] = zb[(size_t)c * SPB + s];
    }
    __syncthreads();
#pragma unroll
    for (int j = 0; j < 8; ++j) {
        int gid = j * 256 + t;     // nl*64 + fg
        int nl = gid >> 6, fg = gid & 63;
        float4 v = *(const float4*)(&Zs[nl][fg * 4]);
        *(float4*)(&zf[(size_t)(n0 + nl) * 256 + fg * 4]) = v;
    }
}

// ---------------------------------------------------------------------------
// MFMA assign, L2-direct, high-intensity: 128 thr = 2 independent waves, each
// wave owns 64 rows (4 x 16-row A-sets, 128 A-VGPRs). B fragments stream from
// the L2-resident eimg through a register double-buffer whose prefetch is
// pinned with sched_barrier(0) (stops the scheduler sinking the loads — R8's
// VGPR=88 showed the dbuf was compiled away). en2 prefetched alongside B.
// 32 MFMAs per chunk (~350cyc) cover the L2 latency of the next chunk's loads.
#define LOADB(Bd, en_, t_)                                                     \
    {                                                                          \
        const char* gb = (const char*)eimg + (size_t)(t_) * 8192 + lane16;     \
        _Pragma("unroll")                                                      \
        for (int kc = 0; kc < 8; ++kc)                                         \
            Bd[kc] = *(const f16x8*)(gb + kc * 1024);                          \
        en_ = en2[(t_) * 16 + (lane & 15)] + 512.0f;                           \
    }

#define COMPUTE(Bd, en_, t_)                                                   \
    {                                                                          \
        f32x4 acc0 = {}, acc1 = {}, acc2 = {}, acc3 = {};                      \
        _Pragma("unroll")                                                      \
        for (int kc = 0; kc < 8; ++kc) {                                       \
            acc0 = __builtin_amdgcn_mfma_f32_16x16x32_f16(A[0][kc], Bd[kc], acc0, 0, 0, 0); \
            acc1 = __builtin_amdgcn_mfma_f32_16x16x32_f16(A[1][kc], Bd[kc], acc1, 0, 0, 0); \
            acc2 = __builtin_amdgcn_mfma_f32_16x16x32_f16(A[2][kc], Bd[kc], acc2, 0, 0, 0); \
            acc3 = __builtin_amdgcn_mfma_f32_16x16x32_f16(A[3][kc], Bd[kc], acc3, 0, 0, 0); \
        }                                                                      \
        const unsigned int tag = (unsigned int)((t_) * 16 + (lane & 15));      \
        _Pragma("unroll")                                                      \
        for (int q = 0; q < 4; ++q) {                                          \
            float d0 = fmaf(-2.f, acc0[q], en_);                               \
            unsigned int du0 = (__float_as_uint(d0) & 0xFFFFF800u) | tag;      \
            m2a[0][q] = umn(m2a[0][q], umx(m1a[0][q], du0));                   \
            m1a[0][q] = umn(m1a[0][q], du0);                                   \
            float d1 = fmaf(-2.f, acc1[q], en_);                               \
            unsigned int du1 = (__float_as_uint(d1) & 0xFFFFF800u) | tag;      \
            m2a[1][q] = umn(m2a[1][q], umx(m1a[1][q], du1));                   \
            m1a[1][q] = umn(m1a[1][q], du1);                                   \
            float d2 = fmaf(-2.f, acc2[q], en_);                               \
            unsigned int du2 = (__float_as_uint(d2) & 0xFFFFF800u) | tag;      \
            m2a[2][q] = umn(m2a[2][q], umx(m1a[2][q], du2));                   \
            m1a[2][q] = umn(m1a[2][q], du2);                                   \
            float d3 = fmaf(-2.f, acc3[q], en_);                               \
            unsigned int du3 = (__float_as_uint(d3) & 0xFFFFF800u) | tag;      \
            m2a[3][q] = umn(m2a[3][q], umx(m1a[3][q], du3));                   \
            m1a[3][q] = umn(m1a[3][q], du3);                                   \
        }                                                                      \
    }

#define FLUSH(book, fo, io, cb, rl)                                            \
    {                                                                          \
        _Pragma("unroll")                                                      \
        for (int rg = 0; rg < 4; ++rg)                                         \
        _Pragma("unroll")                                                      \
        for (int q = 0; q < 4; ++q) {                                          \
            unsigned int v1 = m1a[rg][q], v2 = m2a[rg][q];                     \
            _Pragma("unroll")                                                  \
            for (int m = 8; m >= 1; m >>= 1) {                                 \
                unsigned int o1 = (unsigned int)__shfl_xor((int)v1, m);        \
                unsigned int o2 = (unsigned int)__shfl_xor((int)v2, m);        \
                v2 = umn(umn(v2, o2), umx(v1, o1));                            \
                v1 = umn(v1, o1);                                              \
            }                                                                  \
            if ((lane & 15) == 0) {                                            \
                int kw = (int)(v1 & 0x7FFu) - ((book) ? KS : 0);               \
                int n = n0 + rg * 16 + (lane >> 4) * 4 + q;                    \
                fo[n] = (float)kw;                                             \
                io[n] = kw;                                                    \
                atomicAdd(&cb[kw], 1);                                         \
                if ((v1 >> 11) + 4 > (v2 >> 11)) {                             \
                    int k2w = (int)(v2 & 0x7FFu) - ((book) ? KS : 0);          \
                    int pp = atomicAdd(&rescue_cnt[book], 1);                  \
                    if (pp < 65536) rl[pp] = n | (k2w << 16);                  \
                }                                                              \
            }                                                                  \
            m1a[rg][q] = 0xFFFFFFFFu; m2a[rg][q] = 0xFFFFFFFFu;                \
        }                                                                      \
    }

__launch_bounds__(128, 1)
__global__ void assign_kernel(const float* __restrict__ zf, const unsigned short* __restrict__ eimg,
                              const float* __restrict__ en2,
                              float* __restrict__ sidx_f, float* __restrict__ yidx_f,
                              int* __restrict__ sidx_i, int* __restrict__ yidx_i,
                              int* __restrict__ cnt_s, int* __restrict__ cnt_y,
                              int* __restrict__ rescue_cnt,
                              int* __restrict__ rlist_s, int* __restrict__ rlist_y) {
    const int tid = threadIdx.x, wave = tid >> 6, lane = tid & 63;
    const int n0 = blockIdx.x * 128 + wave * 64;
    const size_t lane16 = (size_t)(lane * 16);

    // A fragments from zf: 4 row-groups x 8 k-chunks (vectorized float4 loads)
    f16x8 A[4][8];
#pragma unroll
    for (int rg = 0; rg < 4; ++rg) {
        const float* zr = zf + (size_t)(n0 + rg * 16 + (lane & 15)) * 256 + (lane >> 4) * 8;
#pragma unroll
        for (int kc = 0; kc < 8; ++kc) {
            float4 f0 = *(const float4*)(zr + kc * 32);
            float4 f1 = *(const float4*)(zr + kc * 32 + 4);
            f16x8 a;
            a[0] = (_Float16)f0.x; a[1] = (_Float16)f0.y;
            a[2] = (_Float16)f0.z; a[3] = (_Float16)f0.w;
            a[4] = (_Float16)f1.x; a[5] = (_Float16)f1.y;
            a[6] = (_Float16)f1.z; a[7] = (_Float16)f1.w;
            A[rg][kc] = a;
        }
    }

    unsigned int m1a[4][4], m2a[4][4];
#pragma unroll
    for (int rg = 0; rg < 4; ++rg)
#pragma unroll
        for (int q = 0; q < 4; ++q) { m1a[rg][q] = 0xFFFFFFFFu; m2a[rg][q] = 0xFFFFFFFFu; }

    f16x8 B0[8], B1[8];
    float enA, enB;
    LOADB(B0, enA, 0);
    __builtin_amdgcn_sched_barrier(0);

#pragma unroll 1
    for (int t = 0; t < 96; t += 2) {
        // even chunk t from B0; prefetch t+1 into B1 (pinned before compute)
        if (t + 1 < 96) LOADB(B1, enB, t + 1);
        __builtin_amdgcn_sched_barrier(0);
        COMPUTE(B0, enA, t);
        // odd chunk t+1 from B1; prefetch t+2 into B0
        if (t + 2 < 96) LOADB(B0, enA, t + 2);
        __builtin_amdgcn_sched_barrier(0);
        COMPUTE(B1, enB, t + 1);
        if (t + 1 == 63) FLUSH(0, sidx_f, sidx_i, cnt_s, rlist_s);
    }
    FLUSH(1, yidx_f, yidx_i, cnt_y, rlist_y);
}

// ---------------------------------------------------------------------------
// Exact-fp32 top-2 re-rank for near-tie rows (both books in one launch):
// one wave per flagged row, compares only {k1, k2} using contiguous zf rows.
__global__ void rescue2_kernel(const float* __restrict__ zf,
                               const float* __restrict__ Es, const float* __restrict__ Ey,
                               const float* __restrict__ en2, const int* __restrict__ rcnt,
                               const int* __restrict__ rlist_s, const int* __restrict__ rlist_y,
                               float* __restrict__ sidx_f, float* __restrict__ yidx_f,
                               int* __restrict__ sidx_i, int* __restrict__ yidx_i,
                               int* __restrict__ cnt_s, int* __restrict__ cnt_y) {
    int cs = rcnt[0]; if (cs > 65536) cs = 65536;
    int cy = rcnt[1]; if (cy > 65536) cy = 65536;
    int total = cs + cy;
    const int lane = threadIdx.x & 63;
    const int nw = (gridDim.x * blockDim.x) >> 6;
    for (int e = (int)((blockIdx.x * blockDim.x + threadIdx.x) >> 6); e < total; e += nw) {
        int book = (e >= cs);
        unsigned int ent = (unsigned int)(book ? rlist_y[e - cs] : rlist_s[e]);
        int n  = (int)(ent & 0xFFFFu);
        int k2 = (int)(ent >> 16);
        int* idx_i = book ? yidx_i : sidx_i;
        float* idx_f = book ? yidx_f : sidx_f;
        int* cnt = book ? cnt_y : cnt_s;
        const float* E = book ? Ey : Es;
        const float* en2k = book ? (en2 + KS) : en2;
        int k1 = idx_i[n];
        float4 zv = *(const float4*)(zf + (size_t)n * 256 + lane * 4);
        float4 a  = *(const float4*)(E + (size_t)k1 * 256 + lane * 4);
        float4 c  = *(const float4*)(E + (size_t)k2 * 256 + lane * 4);
        float d1 = zv.x * a.x + zv.y * a.y + zv.z * a.z + zv.w * a.w;
        float d2 = zv.x * c.x + zv.y * c.y + zv.z * c.z + zv.w * c.w;
#pragma unroll
        for (int off = 32; off > 0; off >>= 1) {
            d1 += __shfl_down(d1, off);
            d2 += __shfl_down(d2, off);
        }
        if (lane == 0) {
            float dist1 = en2k[k1] - 2.f * d1;
            float dist2 = en2k[k2] - 2.f * d2;
            int nk = (dist2 < dist1 || (dist2 == dist1 && k2 < k1)) ? k2 : k1;
            if (nk != k1) {
                atomicSub(&cnt[k1], 1);
                atomicAdd(&cnt[nk], 1);
                idx_i[n] = nk;
                idx_f[n] = (float)nk;
            }
        }
    }
}

// ---------------------------------------------------------------------------
// Per-codebook: prefix-sum of counts (sort bases) + EMA balance scale.
__global__ void scanbal_kernel(const float* __restrict__ cs_in, const float* __restrict__ cy_in,
                               const int* __restrict__ cnt_s, const int* __restrict__ cnt_y,
                               int* __restrict__ base_s, int* __restrict__ base_y,
                               int* __restrict__ cur_s, int* __restrict__ cur_y,
                               float* __restrict__ scale_s, float* __restrict__ scale_y) {
    __shared__ int   sc[1024];
    __shared__ float sf[1024];
    int K = blockIdx.x ? KY : KS;
    const float* csi = blockIdx.x ? cy_in : cs_in;
    const int*   cnt = blockIdx.x ? cnt_y : cnt_s;
    int* base = blockIdx.x ? base_y : base_s;
    int* cur  = blockIdx.x ? cur_y  : cur_s;
    float* scale = blockIdx.x ? scale_y : scale_s;
    int t = threadIdx.x;
    int c = (t < K) ? cnt[t] : 0;
    float ncs = (t < K) ? (csi[t] * 0.99f + 0.01f * (float)c) : 0.f;
    sc[t] = c;
    __syncthreads();
    for (int off = 1; off < 1024; off <<= 1) {
        int v = sc[t] + ((t >= off) ? sc[t - off] : 0);
        __syncthreads();
        sc[t] = v;
        __syncthreads();
    }
    int incl = sc[t];
    sf[t] = ncs;
    __syncthreads();
    for (int s2 = 512; s2 > 0; s2 >>= 1) {
        if (t < s2) sf[t] += sf[t + s2];
        __syncthreads();
    }
    float nsum = sf[0];
    if (t < K) {
        base[t] = incl - c;
        cur[t]  = incl - c;
        float bal = (ncs + 1e-5f) / (nsum + (float)K * 1e-5f) * nsum;
        scale[t] = 1.0f / bal;
    }
}

__global__ void scatter_kernel(const int* __restrict__ si, const int* __restrict__ yi,
                               int* __restrict__ cur_s, int* __restrict__ cur_y,
                               int* __restrict__ perm_s, int* __restrict__ perm_y,
                               int* __restrict__ ksort_s, int* __restrict__ ksort_y) {
    int i = blockIdx.x * 256 + threadIdx.x;
    if (i < NROWS) {
        int k = si[i]; int p = atomicAdd(&cur_s[k], 1);
        perm_s[p] = i; ksort_s[p] = k;
    } else {
        int n = i - NROWS; int k = yi[n]; int p = atomicAdd(&cur_y[k], 1);
        perm_y[p] = n; ksort_y[p] = k;
    }
}

// ---------------------------------------------------------------------------
// Chunked segmented sum over sorted rows: block = 32 sorted positions,
// thread = channel. Runs flushed with fp32 atomics.
__global__ void dw_kernel(const float* __restrict__ zf,
                          const int* __restrict__ perm_s, const int* __restrict__ ksort_s,
                          const int* __restrict__ perm_y, const int* __restrict__ ksort_y,
                          float* __restrict__ dw_s, float* __restrict__ dw_y) {
    __shared__ int keys[33];
    __shared__ int rows[32];
    const int t = threadIdx.x;
    int blk = blockIdx.x;
    const int* perm; const int* ks; float* dw; int p0;
    if (blk < NROWS / 32) { perm = perm_s; ks = ksort_s; dw = dw_s; p0 = blk * 32; }
    else                  { perm = perm_y; ks = ksort_y; dw = dw_y; p0 = (blk - NROWS / 32) * 32; }
    if (t < 32) { keys[t] = ks[p0 + t]; rows[t] = perm[p0 + t]; }
    if (t == 32) keys[32] = -1;
    __syncthreads();
    float acc = 0.f;
#pragma unroll 8
    for (int j = 0; j < 32; ++j) {
        acc += zf[(size_t)rows[j] * 256 + t];
        if (keys[j + 1] != keys[j]) {
            atomicAdd(&dw[(size_t)keys[j] * 256 + t], acc);
            acc = 0.f;
        }
    }
}

__global__ void embnew_kernel(const float* __restrict__ avg_s, const float* __restrict__ avg_y,
                              const float* __restrict__ dw_s, const float* __restrict__ dw_y,
                              const float* __restrict__ scale_s, const float* __restrict__ scale_y,
                              float* __restrict__ emb_s, float* __restrict__ emb_y) {
    int id = blockIdx.x, t = threadIdx.x;
    if (id < KS) { int i = id * 256 + t; emb_s[i] = (avg_s[i] * 0.99f + 0.01f * dw_s[i]) * scale_s[id]; }
    else { int kk = id - KS; int i = kk * 256 + t; emb_y[i] = (avg_y[i] * 0.99f + 0.01f * dw_y[i]) * scale_y[kk]; }
}

// ---------------------------------------------------------------------------
__global__ void gather_kernel(const float* __restrict__ Se, const float* __restrict__ Ye,
                              const int* __restrict__ sidx, const int* __restrict__ yidx,
                              float* __restrict__ zq, float* __restrict__ disacc) {
    __shared__ float qb[256 * 17];
    __shared__ int   si[16], yi[16];
    __shared__ float red[256];
    const int g  = blockIdx.x;        // b*256 + hw
    const int b  = g >> 8;
    const int hw = g & 255;
    const int t  = threadIdx.x;       // channel
    if (t < 16) {
        int n = b * SPB + hw * 16 + t;
        si[t] = sidx[n];
        yi[t] = yidx[n];
    }
    __syncthreads();
    float ns = 0.f, ny = 0.f, dot = 0.f;
#pragma unroll
    for (int d = 0; d < 16; ++d) {
        float s = Se[(size_t)si[d] * CDIM + t];
        float y = Ye[(size_t)yi[d] * CDIM + t];
        ns  = fmaf(s, s, ns);
        ny  = fmaf(y, y, ny);
        dot = fmaf(s, y, dot);
        qb[t * 17 + d] = 0.5f * (s + y);
    }
    float den = fmaxf(sqrtf(ns), 1e-12f) * fmaxf(sqrtf(ny), 1e-12f);
    float val = dot / den;
    red[t] = val * val;
    __syncthreads();
    for (int s = 128; s > 0; s >>= 1) {
        if (t < s) red[t] += red[t + s];
        __syncthreads();
    }
    if (t == 0) atomicAdd(disacc, red[0]);
    float* zg = zq + (size_t)b * CDIM * SPB + hw * 16;
#pragma unroll
    for (int j = 0; j < 16; ++j) {
        int e = j * 256 + t;
        int c = e >> 4, d = e & 15;
        zg[(size_t)c * SPB + d] = qb[c * 17 + d];
    }
}

__global__ void fin_kernel(const float* __restrict__ disacc, float* __restrict__ out_dis) {
    *out_dis = *disacc * (1.0f / 1048576.0f);
}

// ---------------------------------------------------------------------------
extern "C" void kernel_launch(void* const* d_in, const int* in_sizes, int n_in,
                              void* d_out, int out_size, void* d_ws, size_t ws_size,
                              hipStream_t stream) {
    const float* z     = (const float*)d_in[0];
    const float* Es    = (const float*)d_in[1];
    const float* Ey    = (const float*)d_in[2];
    const float* s_cs  = (const float*)d_in[3];
    const float* y_cs  = (const float*)d_in[4];
    const float* s_avg = (const float*)d_in[5];
    const float* y_avg = (const float*)d_in[6];
    float* out = (float*)d_out;
    char*  w   = (char*)d_ws;

    unsigned short* eimg = (unsigned short*)(w + WB_EIMG);
    float* en2    = (float*)(w + WB_EN2);
    int* idxs_i   = (int*)(w + WB_IDXS_I);
    int* idxy_i   = (int*)(w + WB_IDXY_I);
    int* cnt_s    = (int*)(w + WB_CNT_S);
    int* cnt_y    = (int*)(w + WB_CNT_Y);
    int* r_cnt    = (int*)(w + WB_RESCUE_CNT);
    int* rlist_s  = (int*)(w + WB_RLIST_S);
    int* rlist_y  = (int*)(w + WB_RLIST_Y);
    int* base_s   = (int*)(w + WB_BASE_S);
    int* base_y   = (int*)(w + WB_BASE_Y);
    int* cur_s    = (int*)(w + WB_CUR_S);
    int* cur_y    = (int*)(w + WB_CUR_Y);
    float* scale_s = (float*)(w + WB_SCALE_S);
    float* scale_y = (float*)(w + WB_SCALE_Y);
    int* perm_s   = (int*)(w + WB_PERM_S);
    int* perm_y   = (int*)(w + WB_PERM_Y);
    int* ksort_s  = (int*)(w + WB_KSORT_S);
    int* ksort_y  = (int*)(w + WB_KSORT_Y);
    float* dw_s   = (float*)(w + WB_DW_S);
    float* dw_y   = (float*)(w + WB_DW_Y);
    float* emb_s  = (float*)(w + WB_EMB_S);
    float* emb_y  = (float*)(w + WB_EMB_Y);

    float* zf     = out + OFF_OUT_ZQ;        // zq region reused as fp32 z^T scratch
    float* sidx_f = out + OFF_OUT_SIDX;
    float* yidx_f = out + OFF_OUT_YIDX;

    hipMemsetAsync(w, 0, WB_ZERO_BYTES, stream);

    prep_e<<<KTOT, 64, 0, stream>>>(Es, Ey, eimg, en2);
    prep_z<<<NROWS / 32, 256, 0, stream>>>(z, zf);

    assign_kernel<<<NROWS / 128, 128, 0, stream>>>(zf, eimg, en2, sidx_f, yidx_f,
                                                   idxs_i, idxy_i, cnt_s, cnt_y,
                                                   r_cnt, rlist_s, rlist_y);

    rescue2_kernel<<<512, 256, 0, stream>>>(zf, Es, Ey, en2, r_cnt, rlist_s, rlist_y,
                                            sidx_f, yidx_f, idxs_i, idxy_i, cnt_s, cnt_y);

    scanbal_kernel<<<2, 1024, 0, stream>>>(s_cs, y_cs, cnt_s, cnt_y, base_s, base_y,
                                           cur_s, cur_y, scale_s, scale_y);
    scatter_kernel<<<2 * NROWS / 256, 256, 0, stream>>>(idxs_i, idxy_i, cur_s, cur_y,
                                                        perm_s, perm_y, ksort_s, ksort_y);
    dw_kernel<<<2 * NROWS / 32, 256, 0, stream>>>(zf, perm_s, ksort_s, perm_y, ksort_y, dw_s, dw_y);
    embnew_kernel<<<KTOT, 256, 0, stream>>>(s_avg, y_avg, dw_s, dw_y, scale_s, scale_y, emb_s, emb_y);
    gather_kernel<<<4096, 256, 0, stream>>>(emb_s, emb_y, idxs_i, idxy_i,
                                            out + OFF_OUT_ZQ, (float*)(w + WB_DISACC));
    fin_kernel<<<1, 1, 0, stream>>>((float*)(w + WB_DISACC), out + OFF_OUT_DIS);
}

// Round 11
// 309.574 us; speedup vs baseline: 1.0941x; 1.0941x over previous
//
#include <hip/hip_runtime.h>
#include <float.h>

// Problem constants
#define NROWS 65536      // B*H*W*D
#define CDIM  256
#define KS    1024
#define KY    512
#define KTOT  1536
#define SPB   4096       // H*W*D per batch

// ---- workspace byte offsets ----
#define WB_CNT_S       0         // 1024 int
#define WB_CNT_Y       4096      // 512 int
#define WB_RESCUE_CNT  6144      // 2 int
#define WB_DISACC      6152      // 1 float
#define WB_DW_S        6400      // 1024*256 f32
#define WB_DW_Y        1054976   // 512*256 f32
#define WB_ZERO_BYTES  1579264   // memset [0, here): cnt, rescue_cnt, disacc, dw
#define WB_EIMG        1579264   // 96 chunks * 8192 B (fp16 image, 16 codes/chunk)
#define WB_EN2         2365696   // 1536 f32
#define WB_IDXS_I      2371840   // 65536 int
#define WB_IDXY_I      2633984   // 65536 int
#define WB_RLIST_S     2896128   // 65536 int
#define WB_RLIST_Y     3158272   // 65536 int
#define WB_BASE_S      3420416   // 1024 int
#define WB_BASE_Y      3424512   // 512 int
#define WB_CUR_S       3426560   // 1024 int
#define WB_CUR_Y       3430656   // 512 int
#define WB_SCALE_S     3432704   // 1024 f32
#define WB_SCALE_Y     3436800   // 512 f32
#define WB_PERM_S      3438848   // 65536 int
#define WB_PERM_Y      3700992   // 65536 int
#define WB_KSORT_S     3963136   // 65536 int
#define WB_KSORT_Y     4225280   // 65536 int
#define WB_EMB_S       4487424   // 1024*256 f32
#define WB_EMB_Y       5536000   // 512*256 f32

// ---- output float offsets ----
#define OFF_OUT_ZQ   0
#define OFF_OUT_DIS  16777216
#define OFF_OUT_SIDX 16777217
#define OFF_OUT_YIDX 16842753

typedef __attribute__((ext_vector_type(8)))  _Float16 f16x8;
typedef __attribute__((ext_vector_type(4)))  float    f32x4;

__device__ __forceinline__ unsigned int umn(unsigned int a, unsigned int b) { return a < b ? a : b; }
__device__ __forceinline__ unsigned int umx(unsigned int a, unsigned int b) { return a > b ? a : b; }

// ---------------------------------------------------------------------------
// Codebook prep -> fp16 fragment image for 16x16x32 MFMA B-operand.
__global__ void prep_e(const float* __restrict__ Es, const float* __restrict__ Ey,
                       unsigned short* __restrict__ eimg, float* __restrict__ en2) {
    int k = blockIdx.x;            // 0..1535 global code
    int lane = threadIdx.x;        // 64
    const float* E = (k < KS) ? (Es + (size_t)k * CDIM) : (Ey + (size_t)(k - KS) * CDIM);
    float4 v = *(const float4*)(E + lane * 4);
    float nrm = v.x * v.x + v.y * v.y + v.z * v.z + v.w * v.w;
#pragma unroll
    for (int off = 32; off > 0; off >>= 1) nrm += __shfl_down(nrm, off);
    if (lane == 0) en2[k] = nrm;

    unsigned short q0 = __builtin_bit_cast(unsigned short, (_Float16)v.x);
    unsigned short q1 = __builtin_bit_cast(unsigned short, (_Float16)v.y);
    unsigned short q2 = __builtin_bit_cast(unsigned short, (_Float16)v.z);
    unsigned short q3 = __builtin_bit_cast(unsigned short, (_Float16)v.w);
    uint2 hp = make_uint2((unsigned)q0 | ((unsigned)q1 << 16),
                          (unsigned)q2 | ((unsigned)q3 << 16));

    int c0 = lane * 4;
    int kc = c0 >> 5, g = (c0 >> 3) & 3, j0 = c0 & 7;   // j0 in {0,4}
    size_t byteoff = (size_t)(k >> 4) * 8192 + (size_t)kc * 1024
                   + (size_t)(g * 16 + (k & 15)) * 16 + (size_t)j0 * 2;
    *(uint2*)((char*)eimg + byteoff) = hp;
}

// ---------------------------------------------------------------------------
// Transpose z -> zf[n][c] fp32 (written into d_out zq region as scratch).
__global__ void prep_z(const float* __restrict__ z, float* __restrict__ zf) {
    __shared__ float Zs[32][257];
    int blk = blockIdx.x;          // 2048
    int n0 = blk * 32, b = n0 >> 12, s0 = n0 & 4095;
    int t = threadIdx.x;
    const float* zb = z + (size_t)b * CDIM * SPB + s0;
#pragma unroll
    for (int i = 0; i < 32; ++i) {
        int l = i * 256 + t;       // c*32 + s
        int c = l >> 5, s = l & 31;
        Zs[s][c] = zb[(size_t)c * SPB + s];
    }
    __syncthreads();
#pragma unroll
    for (int j = 0; j < 8; ++j) {
        int gid = j * 256 + t;     // nl*64 + fg
        int nl = gid >> 6, fg = gid & 63;
        float4 v = *(const float4*)(&Zs[nl][fg * 4]);
        *(float4*)(&zf[(size_t)(n0 + nl) * 256 + fg * 4]) = v;
    }
}

// ---------------------------------------------------------------------------
// MFMA assign, L2-direct with MANUAL pipeline: 256 thr = 4 independent waves
// x 32 rows. B stream loaded via inline-asm global_load_dwordx4 into named
// register triple-buffers (compiler cannot sink/serialize them — R8/R9 showed
// hipcc compiles away source-level dbuf, VGPR=88/152). Depth-2 prefetch,
// counted s_waitcnt vmcnt(18) (9 ops/chunk: 8 B + 1 en2). vmcnt waits leave
// the NEWEST 18 ops in flight, so interleaved FLUSH stores/atomics (older)
// are also drained — safe. sched_barrier(0) after each wait (rule #18).
// R10 bugfix: book-S flush now fires at T==63 (chunk 63 = COMPUTE(B0) of the
// T=63 iteration); the old `T+2==63` guard never fired (T steps by 3), so
// sidx stayed poisoned -> scatter atomicAdd at 0xAAAAAAAA -> memory fault.
#define LOADB(Bd, en_, t_)                                                     \
    {                                                                          \
        const char* gb0 = (const char*)eimg + (size_t)(t_) * 8192 + lane16;    \
        const char* gb1 = gb0 + 4096;                                          \
        const char* ep  = (const char*)en2 + (size_t)(((t_) << 4) + (lane & 15)) * 4; \
        asm volatile(                                                          \
            "global_load_dwordx4 %0, %8, off\n\t"                              \
            "global_load_dwordx4 %1, %8, off offset:1024\n\t"                  \
            "global_load_dwordx4 %2, %8, off offset:2048\n\t"                  \
            "global_load_dwordx4 %3, %8, off offset:3072\n\t"                  \
            "global_load_dwordx4 %4, %9, off\n\t"                              \
            "global_load_dwordx4 %5, %9, off offset:1024\n\t"                  \
            "global_load_dwordx4 %6, %9, off offset:2048\n\t"                  \
            "global_load_dwordx4 %7, %9, off offset:3072"                      \
            : "=v"(Bd[0]), "=v"(Bd[1]), "=v"(Bd[2]), "=v"(Bd[3]),              \
              "=v"(Bd[4]), "=v"(Bd[5]), "=v"(Bd[6]), "=v"(Bd[7])               \
            : "v"(gb0), "v"(gb1));                                             \
        asm volatile("global_load_dword %0, %1, off" : "=v"(en_) : "v"(ep));   \
    }

#define WAITP(n)                                                               \
    asm volatile("s_waitcnt vmcnt(" #n ")");                                   \
    __builtin_amdgcn_sched_barrier(0);

#define COMPUTE(Bd, en_, t_)                                                   \
    {                                                                          \
        f32x4 acc0 = {}, acc1 = {};                                            \
        __builtin_amdgcn_s_setprio(1);                                         \
        _Pragma("unroll")                                                      \
        for (int kc = 0; kc < 8; ++kc) {                                       \
            f16x8 Bf = __builtin_bit_cast(f16x8, Bd[kc]);                      \
            acc0 = __builtin_amdgcn_mfma_f32_16x16x32_f16(A[0][kc], Bf, acc0, 0, 0, 0); \
            acc1 = __builtin_amdgcn_mfma_f32_16x16x32_f16(A[1][kc], Bf, acc1, 0, 0, 0); \
        }                                                                      \
        __builtin_amdgcn_s_setprio(0);                                         \
        const float en0 = en_ + 512.0f;                                        \
        const unsigned int tag = (unsigned int)(((t_) << 4) + (lane & 15));    \
        _Pragma("unroll")                                                      \
        for (int q = 0; q < 4; ++q) {                                          \
            float d0 = fmaf(-2.f, acc0[q], en0);                               \
            unsigned int du0 = (__float_as_uint(d0) & 0xFFFFF800u) | tag;      \
            m2a[0][q] = umn(m2a[0][q], umx(m1a[0][q], du0));                   \
            m1a[0][q] = umn(m1a[0][q], du0);                                   \
            float d1 = fmaf(-2.f, acc1[q], en0);                               \
            unsigned int du1 = (__float_as_uint(d1) & 0xFFFFF800u) | tag;      \
            m2a[1][q] = umn(m2a[1][q], umx(m1a[1][q], du1));                   \
            m1a[1][q] = umn(m1a[1][q], du1);                                   \
        }                                                                      \
    }

#define FLUSH(book, fo, io, cb, rl)                                            \
    {                                                                          \
        _Pragma("unroll")                                                      \
        for (int rg = 0; rg < 2; ++rg)                                         \
        _Pragma("unroll")                                                      \
        for (int q = 0; q < 4; ++q) {                                          \
            unsigned int v1 = m1a[rg][q], v2 = m2a[rg][q];                     \
            _Pragma("unroll")                                                  \
            for (int m = 8; m >= 1; m >>= 1) {                                 \
                unsigned int o1 = (unsigned int)__shfl_xor((int)v1, m);        \
                unsigned int o2 = (unsigned int)__shfl_xor((int)v2, m);        \
                v2 = umn(umn(v2, o2), umx(v1, o1));                            \
                v1 = umn(v1, o1);                                              \
            }                                                                  \
            if ((lane & 15) == 0) {                                            \
                int kw = (int)(v1 & 0x7FFu) - ((book) ? KS : 0);               \
                int n = n0 + rg * 16 + (lane >> 4) * 4 + q;                    \
                fo[n] = (float)kw;                                             \
                io[n] = kw;                                                    \
                atomicAdd(&cb[kw], 1);                                         \
                if ((v1 >> 11) + 4 > (v2 >> 11)) {                             \
                    int k2w = (int)(v2 & 0x7FFu) - ((book) ? KS : 0);          \
                    int pp = atomicAdd(&rescue_cnt[book], 1);                  \
                    if (pp < 65536) rl[pp] = n | (k2w << 16);                  \
                }                                                              \
            }                                                                  \
            m1a[rg][q] = 0xFFFFFFFFu; m2a[rg][q] = 0xFFFFFFFFu;                \
        }                                                                      \
    }

__launch_bounds__(256, 2)
__global__ void assign_kernel(const float* __restrict__ zf, const unsigned short* __restrict__ eimg,
                              const float* __restrict__ en2,
                              float* __restrict__ sidx_f, float* __restrict__ yidx_f,
                              int* __restrict__ sidx_i, int* __restrict__ yidx_i,
                              int* __restrict__ cnt_s, int* __restrict__ cnt_y,
                              int* __restrict__ rescue_cnt,
                              int* __restrict__ rlist_s, int* __restrict__ rlist_y) {
    const int tid = threadIdx.x, wave = tid >> 6, lane = tid & 63;
    const int n0 = blockIdx.x * 128 + wave * 32;
    const size_t lane16 = (size_t)(lane * 16);

    // A fragments from zf: 2 row-groups x 8 k-chunks (vectorized float4 loads)
    f16x8 A[2][8];
#pragma unroll
    for (int rg = 0; rg < 2; ++rg) {
        const float* zr = zf + (size_t)(n0 + rg * 16 + (lane & 15)) * 256 + (lane >> 4) * 8;
#pragma unroll
        for (int kc = 0; kc < 8; ++kc) {
            float4 f0 = *(const float4*)(zr + kc * 32);
            float4 f1 = *(const float4*)(zr + kc * 32 + 4);
            f16x8 a;
            a[0] = (_Float16)f0.x; a[1] = (_Float16)f0.y;
            a[2] = (_Float16)f0.z; a[3] = (_Float16)f0.w;
            a[4] = (_Float16)f1.x; a[5] = (_Float16)f1.y;
            a[6] = (_Float16)f1.z; a[7] = (_Float16)f1.w;
            A[rg][kc] = a;
        }
    }

    unsigned int m1a[2][4], m2a[2][4];
#pragma unroll
    for (int rg = 0; rg < 2; ++rg)
#pragma unroll
        for (int q = 0; q < 4; ++q) { m1a[rg][q] = 0xFFFFFFFFu; m2a[rg][q] = 0xFFFFFFFFu; }

    f32x4 B0[8], B1[8], B2[8];
    float en0v, en1v, en2v;

    // prologue: chunks 0,1 in flight (18 vm ops)
    LOADB(B0, en0v, 0);
    LOADB(B1, en1v, 1);

    // Steady state: issue chunk t+2, wait so chunk t is done (newest 18 =
    // chunks t+1,t+2), compute chunk t. Prefetch overrun (chunks 96,97) lands
    // in the ws region after eimg (en2/idx) — valid memory, never computed.
#pragma unroll 1
    for (int T = 0; T < 96; T += 3) {
        LOADB(B2, en2v, T + 2);
        WAITP(18);
        COMPUTE(B0, en0v, T);
        if (T == 63) FLUSH(0, sidx_f, sidx_i, cnt_s, rlist_s);   // chunk 63 = last S chunk
        LOADB(B0, en0v, T + 3);
        WAITP(18);
        COMPUTE(B1, en1v, T + 1);
        LOADB(B1, en1v, T + 4);
        WAITP(18);
        COMPUTE(B2, en2v, T + 2);
    }
    FLUSH(1, yidx_f, yidx_i, cnt_y, rlist_y);
}

// ---------------------------------------------------------------------------
// Exact-fp32 top-2 re-rank for near-tie rows (both books in one launch).
__global__ void rescue2_kernel(const float* __restrict__ zf,
                               const float* __restrict__ Es, const float* __restrict__ Ey,
                               const float* __restrict__ en2, const int* __restrict__ rcnt,
                               const int* __restrict__ rlist_s, const int* __restrict__ rlist_y,
                               float* __restrict__ sidx_f, float* __restrict__ yidx_f,
                               int* __restrict__ sidx_i, int* __restrict__ yidx_i,
                               int* __restrict__ cnt_s, int* __restrict__ cnt_y) {
    int cs = rcnt[0]; if (cs > 65536) cs = 65536;
    int cy = rcnt[1]; if (cy > 65536) cy = 65536;
    int total = cs + cy;
    const int lane = threadIdx.x & 63;
    const int nw = (gridDim.x * blockDim.x) >> 6;
    for (int e = (int)((blockIdx.x * blockDim.x + threadIdx.x) >> 6); e < total; e += nw) {
        int book = (e >= cs);
        unsigned int ent = (unsigned int)(book ? rlist_y[e - cs] : rlist_s[e]);
        int n  = (int)(ent & 0xFFFFu);
        int k2 = (int)(ent >> 16);
        int* idx_i = book ? yidx_i : sidx_i;
        float* idx_f = book ? yidx_f : sidx_f;
        int* cnt = book ? cnt_y : cnt_s;
        const float* E = book ? Ey : Es;
        const float* en2k = book ? (en2 + KS) : en2;
        int k1 = idx_i[n];
        float4 zv = *(const float4*)(zf + (size_t)n * 256 + lane * 4);
        float4 a  = *(const float4*)(E + (size_t)k1 * 256 + lane * 4);
        float4 c  = *(const float4*)(E + (size_t)k2 * 256 + lane * 4);
        float d1 = zv.x * a.x + zv.y * a.y + zv.z * a.z + zv.w * a.w;
        float d2 = zv.x * c.x + zv.y * c.y + zv.z * c.z + zv.w * c.w;
#pragma unroll
        for (int off = 32; off > 0; off >>= 1) {
            d1 += __shfl_down(d1, off);
            d2 += __shfl_down(d2, off);
        }
        if (lane == 0) {
            float dist1 = en2k[k1] - 2.f * d1;
            float dist2 = en2k[k2] - 2.f * d2;
            int nk = (dist2 < dist1 || (dist2 == dist1 && k2 < k1)) ? k2 : k1;
            if (nk != k1) {
                atomicSub(&cnt[k1], 1);
                atomicAdd(&cnt[nk], 1);
                idx_i[n] = nk;
                idx_f[n] = (float)nk;
            }
        }
    }
}

// ---------------------------------------------------------------------------
// Per-codebook: prefix-sum of counts (sort bases) + EMA balance scale.
__global__ void scanbal_kernel(const float* __restrict__ cs_in, const float* __restrict__ cy_in,
                               const int* __restrict__ cnt_s, const int* __restrict__ cnt_y,
                               int* __restrict__ base_s, int* __restrict__ base_y,
                               int* __restrict__ cur_s, int* __restrict__ cur_y,
                               float* __restrict__ scale_s, float* __restrict__ scale_y) {
    __shared__ int   sc[1024];
    __shared__ float sf[1024];
    int K = blockIdx.x ? KY : KS;
    const float* csi = blockIdx.x ? cy_in : cs_in;
    const int*   cnt = blockIdx.x ? cnt_y : cnt_s;
    int* base = blockIdx.x ? base_y : base_s;
    int* cur  = blockIdx.x ? cur_y  : cur_s;
    float* scale = blockIdx.x ? scale_y : scale_s;
    int t = threadIdx.x;
    int c = (t < K) ? cnt[t] : 0;
    float ncs = (t < K) ? (csi[t] * 0.99f + 0.01f * (float)c) : 0.f;
    sc[t] = c;
    __syncthreads();
    for (int off = 1; off < 1024; off <<= 1) {
        int v = sc[t] + ((t >= off) ? sc[t - off] : 0);
        __syncthreads();
        sc[t] = v;
        __syncthreads();
    }
    int incl = sc[t];
    sf[t] = ncs;
    __syncthreads();
    for (int s2 = 512; s2 > 0; s2 >>= 1) {
        if (t < s2) sf[t] += sf[t + s2];
        __syncthreads();
    }
    float nsum = sf[0];
    if (t < K) {
        base[t] = incl - c;
        cur[t]  = incl - c;
        float bal = (ncs + 1e-5f) / (nsum + (float)K * 1e-5f) * nsum;
        scale[t] = 1.0f / bal;
    }
}

__global__ void scatter_kernel(const int* __restrict__ si, const int* __restrict__ yi,
                               int* __restrict__ cur_s, int* __restrict__ cur_y,
                               int* __restrict__ perm_s, int* __restrict__ perm_y,
                               int* __restrict__ ksort_s, int* __restrict__ ksort_y) {
    int i = blockIdx.x * 256 + threadIdx.x;
    if (i < NROWS) {
        int k = si[i]; int p = atomicAdd(&cur_s[k], 1);
        perm_s[p] = i; ksort_s[p] = k;
    } else {
        int n = i - NROWS; int k = yi[n]; int p = atomicAdd(&cur_y[k], 1);
        perm_y[p] = n; ksort_y[p] = k;
    }
}

// ---------------------------------------------------------------------------
// Chunked segmented sum over sorted rows: block = 32 sorted positions,
// thread = channel. Runs flushed with fp32 atomics.
__global__ void dw_kernel(const float* __restrict__ zf,
                          const int* __restrict__ perm_s, const int* __restrict__ ksort_s,
                          const int* __restrict__ perm_y, const int* __restrict__ ksort_y,
                          float* __restrict__ dw_s, float* __restrict__ dw_y) {
    __shared__ int keys[33];
    __shared__ int rows[32];
    const int t = threadIdx.x;
    int blk = blockIdx.x;
    const int* perm; const int* ks; float* dw; int p0;
    if (blk < NROWS / 32) { perm = perm_s; ks = ksort_s; dw = dw_s; p0 = blk * 32; }
    else                  { perm = perm_y; ks = ksort_y; dw = dw_y; p0 = (blk - NROWS / 32) * 32; }
    if (t < 32) { keys[t] = ks[p0 + t]; rows[t] = perm[p0 + t]; }
    if (t == 32) keys[32] = -1;
    __syncthreads();
    float acc = 0.f;
#pragma unroll 8
    for (int j = 0; j < 32; ++j) {
        acc += zf[(size_t)rows[j] * 256 + t];
        if (keys[j + 1] != keys[j]) {
            atomicAdd(&dw[(size_t)keys[j] * 256 + t], acc);
            acc = 0.f;
        }
    }
}

__global__ void embnew_kernel(const float* __restrict__ avg_s, const float* __restrict__ avg_y,
                              const float* __restrict__ dw_s, const float* __restrict__ dw_y,
                              const float* __restrict__ scale_s, const float* __restrict__ scale_y,
                              float* __restrict__ emb_s, float* __restrict__ emb_y) {
    int id = blockIdx.x, t = threadIdx.x;
    if (id < KS) { int i = id * 256 + t; emb_s[i] = (avg_s[i] * 0.99f + 0.01f * dw_s[i]) * scale_s[id]; }
    else { int kk = id - KS; int i = kk * 256 + t; emb_y[i] = (avg_y[i] * 0.99f + 0.01f * dw_y[i]) * scale_y[kk]; }
}

// ---------------------------------------------------------------------------
__global__ void gather_kernel(const float* __restrict__ Se, const float* __restrict__ Ye,
                              const int* __restrict__ sidx, const int* __restrict__ yidx,
                              float* __restrict__ zq, float* __restrict__ disacc) {
    __shared__ float qb[256 * 17];
    __shared__ int   si[16], yi[16];
    __shared__ float red[256];
    const int g  = blockIdx.x;        // b*256 + hw
    const int b  = g >> 8;
    const int hw = g & 255;
    const int t  = threadIdx.x;       // channel
    if (t < 16) {
        int n = b * SPB + hw * 16 + t;
        si[t] = sidx[n];
        yi[t] = yidx[n];
    }
    __syncthreads();
    float ns = 0.f, ny = 0.f, dot = 0.f;
#pragma unroll
    for (int d = 0; d < 16; ++d) {
        float s = Se[(size_t)si[d] * CDIM + t];
        float y = Ye[(size_t)yi[d] * CDIM + t];
        ns  = fmaf(s, s, ns);
        ny  = fmaf(y, y, ny);
        dot = fmaf(s, y, dot);
        qb[t * 17 + d] = 0.5f * (s + y);
    }
    float den = fmaxf(sqrtf(ns), 1e-12f) * fmaxf(sqrtf(ny), 1e-12f);
    float val = dot / den;
    red[t] = val * val;
    __syncthreads();
    for (int s = 128; s > 0; s >>= 1) {
        if (t < s) red[t] += red[t + s];
        __syncthreads();
    }
    if (t == 0) atomicAdd(disacc, red[0]);
    float* zg = zq + (size_t)b * CDIM * SPB + hw * 16;
#pragma unroll
    for (int j = 0; j < 16; ++j) {
        int e = j * 256 + t;
        int c = e >> 4, d = e & 15;
        zg[(size_t)c * SPB + d] = qb[c * 17 + d];
    }
}

__global__ void fin_kernel(const float* __restrict__ disacc, float* __restrict__ out_dis) {
    *out_dis = *disacc * (1.0f / 1048576.0f);
}

// ---------------------------------------------------------------------------
extern "C" void kernel_launch(void* const* d_in, const int* in_sizes, int n_in,
                              void* d_out, int out_size, void* d_ws, size_t ws_size,
                              hipStream_t stream) {
    const float* z     = (const float*)d_in[0];
    const float* Es    = (const float*)d_in[1];
    const float* Ey    = (const float*)d_in[2];
    const float* s_cs  = (const float*)d_in[3];
    const float* y_cs  = (const float*)d_in[4];
    const float* s_avg = (const float*)d_in[5];
    const float* y_avg = (const float*)d_in[6];
    float* out = (float*)d_out;
    char*  w   = (char*)d_ws;

    unsigned short* eimg = (unsigned short*)(w + WB_EIMG);
    float* en2    = (float*)(w + WB_EN2);
    int* idxs_i   = (int*)(w + WB_IDXS_I);
    int* idxy_i   = (int*)(w + WB_IDXY_I);
    int* cnt_s    = (int*)(w + WB_CNT_S);
    int* cnt_y    = (int*)(w + WB_CNT_Y);
    int* r_cnt    = (int*)(w + WB_RESCUE_CNT);
    int* rlist_s  = (int*)(w + WB_RLIST_S);
    int* rlist_y  = (int*)(w + WB_RLIST_Y);
    int* base_s   = (int*)(w + WB_BASE_S);
    int* base_y   = (int*)(w + WB_BASE_Y);
    int* cur_s    = (int*)(w + WB_CUR_S);
    int* cur_y    = (int*)(w + WB_CUR_Y);
    float* scale_s = (float*)(w + WB_SCALE_S);
    float* scale_y = (float*)(w + WB_SCALE_Y);
    int* perm_s   = (int*)(w + WB_PERM_S);
    int* perm_y   = (int*)(w + WB_PERM_Y);
    int* ksort_s  = (int*)(w + WB_KSORT_S);
    int* ksort_y  = (int*)(w + WB_KSORT_Y);
    float* dw_s   = (float*)(w + WB_DW_S);
    float* dw_y   = (float*)(w + WB_DW_Y);
    float* emb_s  = (float*)(w + WB_EMB_S);
    float* emb_y  = (float*)(w + WB_EMB_Y);

    float* zf     = out + OFF_OUT_ZQ;        // zq region reused as fp32 z^T scratch
    float* sidx_f = out + OFF_OUT_SIDX;
    float* yidx_f = out + OFF_OUT_YIDX;

    hipMemsetAsync(w, 0, WB_ZERO_BYTES, stream);

    prep_e<<<KTOT, 64, 0, stream>>>(Es, Ey, eimg, en2);
    prep_z<<<NROWS / 32, 256, 0, stream>>>(z, zf);

    assign_kernel<<<NROWS / 128, 256, 0, stream>>>(zf, eimg, en2, sidx_f, yidx_f,
                                                   idxs_i, idxy_i, cnt_s, cnt_y,
                                                   r_cnt, rlist_s, rlist_y);

    rescue2_kernel<<<512, 256, 0, stream>>>(zf, Es, Ey, en2, r_cnt, rlist_s, rlist_y,
                                            sidx_f, yidx_f, idxs_i, idxy_i, cnt_s, cnt_y);

    scanbal_kernel<<<2, 1024, 0, stream>>>(s_cs, y_cs, cnt_s, cnt_y, base_s, base_y,
                                           cur_s, cur_y, scale_s, scale_y);
    scatter_kernel<<<2 * NROWS / 256, 256, 0, stream>>>(idxs_i, idxy_i, cur_s, cur_y,
                                                        perm_s, perm_y, ksort_s, ksort_y);
    dw_kernel<<<2 * NROWS / 32, 256, 0, stream>>>(zf, perm_s, ksort_s, perm_y, ksort_y, dw_s, dw_y);
    embnew_kernel<<<KTOT, 256, 0, stream>>>(s_avg, y_avg, dw_s, dw_y, scale_s, scale_y, emb_s, emb_y);
    gather_kernel<<<4096, 256, 0, stream>>>(emb_s, emb_y, idxs_i, idxy_i,
                                            out + OFF_OUT_ZQ, (float*)(w + WB_DISACC));
    fin_kernel<<<1, 1, 0, stream>>>((float*)(w + WB_DISACC), out + OFF_OUT_DIS);
}